// Round 10
// baseline (230.102 us; speedup 1.0000x reference)
//
#include <hip/hip_runtime.h>
#include <stdint.h>

#define HID 512
#define NH 8
#define HD 64
#define BATCH 2
#define SEQ 4096
#define M_TOT (BATCH*SEQ)   // 8192
#define NBH (BATCH*NH)      // 16
#define SPLITK 2

typedef __attribute__((ext_vector_type(8))) short short8;
typedef __attribute__((ext_vector_type(4))) float floatx4;
typedef unsigned short u16;

// fp32 -> bf16 (RNE), bit-level
__device__ inline u16 f2bf(float x) {
  unsigned u = __builtin_bit_cast(unsigned, x);
  unsigned r = u + 0x7fff + ((u >> 16) & 1);
  return (u16)(r >> 16);
}

__device__ inline float bf2f(u16 h) {
  unsigned u = ((unsigned)h) << 16;
  return __builtin_bit_cast(float, u);
}

// two fp32 -> packed bf16x2 (RNE) in ONE instruction (lo = bf16(a), hi = bf16(b))
__device__ inline unsigned cvt_pk_bf16(float a, float b) {
  unsigned r;
  asm("v_cvt_pk_bf16_f32 %0, %1, %2" : "=v"(r) : "v"(a), "v"(b));
  return r;
}

__device__ inline void gll16(const void* g, void* l) {
  __builtin_amdgcn_global_load_lds((const __attribute__((address_space(1))) void*)g,
                                   (__attribute__((address_space(3))) void*)l, 16, 0, 0);
}

// swizzled layouts:
// QK (K=32 A/B frags, 1KB wave-contiguous):
//   idx(s,d) = (s>>4)*1024 + (d>>3)*128 + (s&15)*8 + (d&7)
//   frag read byte addr = lane*16  (conflict-free)
// V  (K=32 B frags for 16x16x32 PV):
//   kv slot k(s) = ((s>>2)&3)*8 + ((s>>4)&1)*4 + (s&3)
//   idx(s,d) = (s>>5)*2048 + (d>>4)*512 + (k>>3)*128 + (d&15)*8 + (k&7)
//   frag read byte addr = gg*4096 + dt*1024 + lane*16  (conflict-free)

// ---------------- weight fp32 -> bf16 convert (tiny: 4 x 256 blocks) --------
__global__ void cvt_w(const float* __restrict__ wq, const float* __restrict__ wk,
                      const float* __restrict__ wv, const float* __restrict__ wo,
                      u16* __restrict__ wb) {
  const size_t NW = (size_t)HID * HID;
  int bx = (int)blockIdx.x;
  int w = bx >> 8;                // /256
  int blk = bx & 255;
  const float* src = (w == 0) ? wq : ((w == 1) ? wk : ((w == 2) ? wv : wo));
  u16* dst = wb + (size_t)w * NW;
  int i = (blk * 256 + (int)threadIdx.x) * 4;
  const float4 val = *(const float4*)(src + i);
  union { uint2 u; u16 h[4]; } pk;
  pk.h[0] = f2bf(val.x); pk.h[1] = f2bf(val.y);
  pk.h[2] = f2bf(val.z); pk.h[3] = f2bf(val.w);
  *(uint2*)(dst + i) = pk.u;
}

// ---------------- QKV projection GEMM (BK=64, two-half LDS, fused cvt) ------
// K-step doubled to 64 via As[2]/Bs[2] half-buffers: half the barriers and
// loop iterations, identical per-half fragment addressing (no new bank
// conflicts), identical staging bytes and MFMA count. Halves consumed in
// sequential kq phases so fragment register footprint is unchanged.
__global__ __launch_bounds__(256) void gemm_qkv(
    const float* __restrict__ Xq, const float* __restrict__ Xk, const float* __restrict__ Xv,
    const u16* __restrict__ Wb,
    const float* __restrict__ bq, const float* __restrict__ bk, const float* __restrict__ bv,
    u16* __restrict__ Qp, u16* __restrict__ Kp, u16* __restrict__ Vt) {
  const int z = blockIdx.z;
  const float* X = (z == 0) ? Xq : ((z == 1) ? Xk : Xv);
  const u16* W = Wb + (size_t)z * (HID * HID);
  const float* bias = (z == 0) ? bq : ((z == 1) ? bk : bv);

  __shared__ u16 As[2][128 * 32];
  __shared__ u16 Bs[2][128 * 32];

  const int tid = threadIdx.x;
  const int wid = tid >> 6, lane = tid & 63;
  const int wm = wid >> 1, wn = wid & 1;
  const int quad = lane >> 4, l16 = lane & 15;
  const int m0 = (int)blockIdx.x * 128, n0 = (int)blockIdx.y * 128;
  const int srow = lane >> 2;
  const int scol = (lane & 3) * 8;

  floatx4 acc[4][4];
#pragma unroll
  for (int i = 0; i < 4; i++)
#pragma unroll
    for (int j = 0; j < 4; j++) acc[i][j] = floatx4{0.f, 0.f, 0.f, 0.f};

  for (int k0 = 0; k0 < HID; k0 += 64) {
#pragma unroll
    for (int half = 0; half < 2; half++) {
#pragma unroll
      for (int r = 0; r < 2; r++) {
        int row = r * 64 + wid * 16 + srow;
        const float* srcp = X + (size_t)(m0 + row) * HID + k0 + half * 32 + scol;
        float4 p0 = *(const float4*)srcp;
        float4 p1 = *(const float4*)(srcp + 4);
        union { unsigned u[4]; short8 s; } pka;
        pka.u[0] = cvt_pk_bf16(p0.x, p0.y);
        pka.u[1] = cvt_pk_bf16(p0.z, p0.w);
        pka.u[2] = cvt_pk_bf16(p1.x, p1.y);
        pka.u[3] = cvt_pk_bf16(p1.z, p1.w);
        *(short8*)&As[half][(r * 64 + wid * 16) * 32 + lane * 8] = pka.s;
        gll16(W + (size_t)(n0 + row) * HID + k0 + half * 32 + scol,
              &Bs[half][(r * 64 + wid * 16) * 32]);
      }
    }
    __syncthreads();
#pragma unroll
    for (int kq = 0; kq < 2; kq++) {
      short8 af[4], bf[4];
#pragma unroll
      for (int mt = 0; mt < 4; mt++)
        af[mt] = *(const short8*)&As[kq][(wm * 64 + mt * 16 + l16) * 32 + quad * 8];
#pragma unroll
      for (int nt = 0; nt < 4; nt++)
        bf[nt] = *(const short8*)&Bs[kq][(wn * 64 + nt * 16 + l16) * 32 + quad * 8];
#pragma unroll
      for (int mt = 0; mt < 4; mt++)
#pragma unroll
        for (int nt = 0; nt < 4; nt++)
          acc[mt][nt] = __builtin_amdgcn_mfma_f32_16x16x32_bf16(af[mt], bf[nt], acc[mt][nt], 0, 0, 0);
    }
    __syncthreads();
  }

#pragma unroll
  for (int mt = 0; mt < 4; mt++) {
#pragma unroll
    for (int nt = 0; nt < 4; nt++) {
      int ncol = n0 + wn * 64 + nt * 16 + l16;
      float bias_v = bias[ncol];
      int h = ncol >> 6, d = ncol & 63;
#pragma unroll
      for (int r = 0; r < 4; r++) {
        int mrow = m0 + wm * 64 + mt * 16 + quad * 4 + r;
        float v = acc[mt][nt][r] + bias_v;
        int b = mrow >> 12, s = mrow & (SEQ - 1);
        size_t base = (size_t)(b * NH + h) * SEQ * HD;
        if (z == 2) {
          int kk = ((s >> 2) & 3) * 8 + ((s >> 4) & 1) * 4 + (s & 3);
          size_t idx = base + (size_t)(s >> 5) * 2048 + (d >> 4) * 512
                     + (kk >> 3) * 128 + (d & 15) * 8 + (kk & 7);
          Vt[idx] = f2bf(v);
        } else {
          size_t idx = base + (size_t)(s >> 4) * 1024 + (d >> 3) * 128 + (s & 15) * 8 + (d & 7);
          if (z == 0) Qp[idx] = f2bf(v * 0.18033688f);   // 0.125*log2(e)
          else        Kp[idx] = f2bf(v);
        }
      }
    }
  }
}

// ---------------- output projection GEMM (fused split-K combine) ------------
__global__ __launch_bounds__(256) void gemm_out(
    const u16* __restrict__ Opb, const float* __restrict__ Lp,
    const u16* __restrict__ W,
    const float* __restrict__ bias, float* __restrict__ out) {
  __shared__ u16 As[128 * 32];
  __shared__ u16 Bs[64 * 32];

  const int tid = threadIdx.x;
  const int wid = tid >> 6, lane = tid & 63;
  const int wm = wid >> 1, wn = wid & 1;
  const int quad = lane >> 4, l16 = lane & 15;
  const int m0 = (int)blockIdx.x * 128, n0 = (int)blockIdx.y * 64;
  const int srow = lane >> 2;
  const int scol = (lane & 3) * 8;

  float invl[2][NH];
#pragma unroll
  for (int r = 0; r < 2; r++) {
    int mrow = m0 + r * 64 + wid * 16 + srow;
    int b = mrow >> 12, qq = mrow & (SEQ - 1);
#pragma unroll
    for (int h = 0; h < NH; h++) {
      float s = 0.f;
#pragma unroll
      for (int sp = 0; sp < SPLITK; sp++)
        s += Lp[(size_t)(sp * NBH + b * NH + h) * SEQ + qq];
      invl[r][h] = 1.f / s;
    }
  }

  floatx4 acc[4][2];
#pragma unroll
  for (int i = 0; i < 4; i++)
#pragma unroll
    for (int j = 0; j < 2; j++) acc[i][j] = floatx4{0.f, 0.f, 0.f, 0.f};

#pragma unroll
  for (int kb = 0; kb < 16; kb++) {
    const int k0 = kb * 32;
    const int h = k0 >> 6;                 // compile-time per unrolled iter
    const int d = (k0 + scol) & 63;
#pragma unroll
    for (int r = 0; r < 2; r++) {
      int mrow = m0 + r * 64 + wid * 16 + srow;
      int b = mrow >> 12, qq = mrow & (SEQ - 1);
      int bh = b * NH + h;
      float a0 = 0.f, a1 = 0.f, a2 = 0.f, a3 = 0.f, a4 = 0.f, a5 = 0.f, a6 = 0.f, a7 = 0.f;
#pragma unroll
      for (int sp = 0; sp < SPLITK; sp++) {
        const u16* p = Opb + ((size_t)(sp * NBH + bh) * SEQ + qq) * HD + d;
        short8 vv = *(const short8*)p;
        a0 += bf2f((u16)vv[0]); a1 += bf2f((u16)vv[1]);
        a2 += bf2f((u16)vv[2]); a3 += bf2f((u16)vv[3]);
        a4 += bf2f((u16)vv[4]); a5 += bf2f((u16)vv[5]);
        a6 += bf2f((u16)vv[6]); a7 += bf2f((u16)vv[7]);
      }
      float inv = invl[r][h];
      union { unsigned u[4]; short8 s; } pka;
      pka.u[0] = cvt_pk_bf16(a0 * inv, a1 * inv);
      pka.u[1] = cvt_pk_bf16(a2 * inv, a3 * inv);
      pka.u[2] = cvt_pk_bf16(a4 * inv, a5 * inv);
      pka.u[3] = cvt_pk_bf16(a6 * inv, a7 * inv);
      *(short8*)&As[(r * 64 + wid * 16) * 32 + lane * 8] = pka.s;
    }
    {
      int row = wid * 16 + srow;
      gll16(W + (size_t)(n0 + row) * HID + k0 + scol, &Bs[(wid * 16) * 32]);
    }
    __syncthreads();
    short8 af[4], bfr[2];
#pragma unroll
    for (int mt = 0; mt < 4; mt++)
      af[mt] = *(const short8*)&As[(wm * 64 + mt * 16 + l16) * 32 + quad * 8];
#pragma unroll
    for (int nt = 0; nt < 2; nt++)
      bfr[nt] = *(const short8*)&Bs[(wn * 32 + nt * 16 + l16) * 32 + quad * 8];
#pragma unroll
    for (int mt = 0; mt < 4; mt++)
#pragma unroll
      for (int nt = 0; nt < 2; nt++)
        acc[mt][nt] = __builtin_amdgcn_mfma_f32_16x16x32_bf16(af[mt], bfr[nt], acc[mt][nt], 0, 0, 0);
    __syncthreads();
  }

#pragma unroll
  for (int mt = 0; mt < 4; mt++) {
#pragma unroll
    for (int nt = 0; nt < 2; nt++) {
      int ncol = n0 + wn * 32 + nt * 16 + l16;
      float bias_v = bias[ncol];
#pragma unroll
      for (int r = 0; r < 4; r++) {
        int mrow = m0 + wm * 64 + mt * 16 + quad * 4 + r;
        out[(size_t)mrow * HID + ncol] = acc[mt][nt][r] + bias_v;
      }
    }
  }
}

// ---------------- flash attention v16: v15 body + setprio (T5) --------------
// Per-wave code = verified v10/v15 verbatim; s_setprio(1) wraps the QK and PV
// MFMA clusters so MFMA-issuing waves win SIMD arbitration over waves doing
// softmax VALU / staging (blocks on a SIMD are phase-decorrelated).
__global__ __launch_bounds__(256) void attn_kernel(
    const u16* __restrict__ Qp, const u16* __restrict__ Kp,
    const u16* __restrict__ Vt, u16* __restrict__ Opb, float* __restrict__ Lp) {
  const int bh = blockIdx.y;
  const int sp = blockIdx.z;
  const int q0 = (int)blockIdx.x * 128;
  const u16* Qh = Qp + (size_t)bh * SEQ * HD;
  const u16* Kh = Kp + (size_t)bh * SEQ * HD;
  const u16* Vh = Vt + (size_t)bh * SEQ * HD;

  __shared__ u16 Ks[2][4096];   // 8 KB per buffer: 64 kv x 64 d
  __shared__ u16 Vs[2][4096];

  const int tid = threadIdx.x;
  const int wid = tid >> 6, lane = tid & 63;
  const int quad = lane >> 4, l16 = lane & 15;

  short8 qf[2][2];
#pragma unroll
  for (int kq = 0; kq < 2; kq++)
#pragma unroll
    for (int n = 0; n < 2; n++)
      qf[kq][n] = *(const short8*)(Qh + (size_t)(q0 / 16 + wid * 2 + n) * 1024 + (kq * 4 + quad) * 128 + l16 * 8);

  float l_part[2] = {0.f, 0.f};
  floatx4 o[2][4];
#pragma unroll
  for (int m = 0; m < 2; m++)
#pragma unroll
    for (int dt = 0; dt < 4; dt++) o[m][dt] = floatx4{0.f, 0.f, 0.f, 0.f};

  const int kv_lo = sp * (SEQ / SPLITK), kv_hi = kv_lo + SEQ / SPLITK;

  auto stage = [&](int buf, int kv0) {
    const u16* kg = Kh + (size_t)(kv0 >> 4) * 1024;   // == kv0*64, both layouts
    const u16* vg = Vh + (size_t)(kv0 >> 4) * 1024;
#pragma unroll
    for (int r = 0; r < 2; r++) {
      int c = wid + r * 4;
      gll16(kg + c * 512 + lane * 8, &Ks[buf][c * 512]);
      gll16(vg + c * 512 + lane * 8, &Vs[buf][c * 512]);
    }
  };

  stage(0, kv_lo);
  __syncthreads();

  int ibuf = 0;
  for (int kv0 = kv_lo; kv0 < kv_hi; kv0 += 64) {
    if (kv0 + 64 < kv_hi) stage(ibuf ^ 1, kv0 + 64);

#pragma unroll
    for (int gg = 0; gg < 2; gg++) {             // 32-kv group = score tiles A,B
      const u16* Kb = &Ks[ibuf][gg * 2048];
      short8 akA0 = *(const short8*)&Kb[quad * 128 + l16 * 8];
      short8 akA1 = *(const short8*)&Kb[(4 + quad) * 128 + l16 * 8];
      short8 akB0 = *(const short8*)&Kb[1024 + quad * 128 + l16 * 8];
      short8 akB1 = *(const short8*)&Kb[1024 + (4 + quad) * 128 + l16 * 8];
      short8 vf[4];
#pragma unroll
      for (int dt = 0; dt < 4; dt++)
        vf[dt] = *(const short8*)&Vs[ibuf][gg * 2048 + dt * 512 + quad * 128 + l16 * 8];

      floatx4 stA[2], stB[2];
      __builtin_amdgcn_s_setprio(1);
#pragma unroll
      for (int n = 0; n < 2; n++) {
        stA[n] = __builtin_amdgcn_mfma_f32_16x16x32_bf16(akA0, qf[0][n], floatx4{0.f,0.f,0.f,0.f}, 0, 0, 0);
        stB[n] = __builtin_amdgcn_mfma_f32_16x16x32_bf16(akB0, qf[0][n], floatx4{0.f,0.f,0.f,0.f}, 0, 0, 0);
        stA[n] = __builtin_amdgcn_mfma_f32_16x16x32_bf16(akA1, qf[1][n], stA[n], 0, 0, 0);
        stB[n] = __builtin_amdgcn_mfma_f32_16x16x32_bf16(akB1, qf[1][n], stB[n], 0, 0, 0);
      }
      __builtin_amdgcn_s_setprio(0);

#pragma unroll
      for (int n = 0; n < 2; n++) {
        float a0 = __builtin_amdgcn_exp2f(stA[n][0]);
        float a1 = __builtin_amdgcn_exp2f(stA[n][1]);
        float a2 = __builtin_amdgcn_exp2f(stA[n][2]);
        float a3 = __builtin_amdgcn_exp2f(stA[n][3]);
        float b0 = __builtin_amdgcn_exp2f(stB[n][0]);
        float b1 = __builtin_amdgcn_exp2f(stB[n][1]);
        float b2 = __builtin_amdgcn_exp2f(stB[n][2]);
        float b3 = __builtin_amdgcn_exp2f(stB[n][3]);
        l_part[n] += ((a0 + a1) + (a2 + a3)) + ((b0 + b1) + (b2 + b3));
        union { unsigned u[4]; short8 s; } pk;
        pk.u[0] = cvt_pk_bf16(a0, a1);
        pk.u[1] = cvt_pk_bf16(a2, a3);
        pk.u[2] = cvt_pk_bf16(b0, b1);
        pk.u[3] = cvt_pk_bf16(b2, b3);
        __builtin_amdgcn_s_setprio(1);
#pragma unroll
        for (int dt = 0; dt < 4; dt++)
          o[n][dt] = __builtin_amdgcn_mfma_f32_16x16x32_bf16(pk.s, vf[dt], o[n][dt], 0, 0, 0);
        __builtin_amdgcn_s_setprio(0);
      }
    }
    __syncthreads();
    ibuf ^= 1;
  }

#pragma unroll
  for (int n = 0; n < 2; n++) {
    l_part[n] += __shfl_xor(l_part[n], 16);
    l_part[n] += __shfl_xor(l_part[n], 32);
  }
  u16* Oph = Opb + (size_t)(sp * NBH + bh) * SEQ * HD;
  float* Lph = Lp + (size_t)(sp * NBH + bh) * SEQ;
  if (quad == 0) {
#pragma unroll
    for (int n = 0; n < 2; n++)
      Lph[q0 + wid * 32 + n * 16 + l16] = l_part[n];
  }
#pragma unroll
  for (int m = 0; m < 2; m++) {
#pragma unroll
    for (int r = 0; r < 4; r++) {
      int s = q0 + wid * 32 + m * 16 + quad * 4 + r;
#pragma unroll
      for (int dt = 0; dt < 4; dt++)
        Oph[(size_t)s * HD + dt * 16 + l16] = f2bf(o[m][dt][r]);
    }
  }
}

extern "C" void kernel_launch(void* const* d_in, const int* in_sizes, int n_in,
                              void* d_out, int out_size, void* d_ws, size_t ws_size,
                              hipStream_t stream) {
  const float* q  = (const float*)d_in[0];
  const float* k  = (const float*)d_in[1];
  const float* v  = (const float*)d_in[2];
  const float* Wq = (const float*)d_in[3];
  const float* bq = (const float*)d_in[4];
  const float* Wk = (const float*)d_in[5];
  const float* bk = (const float*)d_in[6];
  const float* Wv = (const float*)d_in[7];
  const float* bv = (const float*)d_in[8];
  const float* Wo = (const float*)d_in[9];
  const float* bo = (const float*)d_in[10];

  u16* wsb = (u16*)d_ws;
  const size_t NW = (size_t)HID * HID;     // 262144
  const size_t NX = (size_t)M_TOT * HID;   // 4194304
  u16* Wb = wsb;            // Wq,Wk,Wv,Wo bf16 (4*NW)
  u16* Qp = wsb + 4 * NW;
  u16* Kp = Qp + NX;
  u16* Vt = Kp + NX;
  u16* Opb = Vt + NX;                          // 2*16*4096*64 bf16 = 16.8 MB
  float* Lp = (float*)(Opb + (size_t)SPLITK * NBH * SEQ * HD);  // 2*16*4096 fp32 = 512 KB

  dim3 blk(256);
  cvt_w<<<dim3(1024), blk, 0, stream>>>(Wq, Wk, Wv, Wo, Wb);
  gemm_qkv<<<dim3(64, 4, 3), blk, 0, stream>>>(q, k, v, Wb, bq, bk, bv, Qp, Kp, Vt);
  attn_kernel<<<dim3(32, NBH, SPLITK), blk, 0, stream>>>(Qp, Kp, Vt, Opb, Lp);
  gemm_out<<<dim3(64, 8), blk, 0, stream>>>(Opb, Lp, Wb + 3 * NW, bo, (float*)d_out);
}

// Round 11
// 223.630 us; speedup vs baseline: 1.0289x; 1.0289x over previous
//
#include <hip/hip_runtime.h>
#include <stdint.h>

#define HID 512
#define NH 8
#define HD 64
#define BATCH 2
#define SEQ 4096
#define M_TOT (BATCH*SEQ)   // 8192
#define NBH (BATCH*NH)      // 16
#define SPLITK 2

typedef __attribute__((ext_vector_type(8))) short short8;
typedef __attribute__((ext_vector_type(4))) float floatx4;
typedef unsigned short u16;

// fp32 -> bf16 (RNE), bit-level
__device__ inline u16 f2bf(float x) {
  unsigned u = __builtin_bit_cast(unsigned, x);
  unsigned r = u + 0x7fff + ((u >> 16) & 1);
  return (u16)(r >> 16);
}

__device__ inline float bf2f(u16 h) {
  unsigned u = ((unsigned)h) << 16;
  return __builtin_bit_cast(float, u);
}

// two fp32 -> packed bf16x2 (RNE) in ONE instruction (lo = bf16(a), hi = bf16(b))
__device__ inline unsigned cvt_pk_bf16(float a, float b) {
  unsigned r;
  asm("v_cvt_pk_bf16_f32 %0, %1, %2" : "=v"(r) : "v"(a), "v"(b));
  return r;
}

__device__ inline void gll16(const void* g, void* l) {
  __builtin_amdgcn_global_load_lds((const __attribute__((address_space(1))) void*)g,
                                   (__attribute__((address_space(3))) void*)l, 16, 0, 0);
}

// swizzled layouts:
// QK (K=32 A/B frags, 1KB wave-contiguous):
//   idx(s,d) = (s>>4)*1024 + (d>>3)*128 + (s&15)*8 + (d&7)
//   frag read byte addr = lane*16  (conflict-free)
// V  (K=32 B frags for 16x16x32 PV):
//   kv slot k(s) = ((s>>2)&3)*8 + ((s>>4)&1)*4 + (s&3)
//   idx(s,d) = (s>>5)*2048 + (d>>4)*512 + (k>>3)*128 + (d&15)*8 + (k&7)
//   frag read byte addr = gg*4096 + dt*1024 + lane*16  (conflict-free)

// ---------------- weight fp32 -> bf16 convert (tiny: 4 x 256 blocks) --------
__global__ void cvt_w(const float* __restrict__ wq, const float* __restrict__ wk,
                      const float* __restrict__ wv, const float* __restrict__ wo,
                      u16* __restrict__ wb) {
  const size_t NW = (size_t)HID * HID;
  int bx = (int)blockIdx.x;
  int w = bx >> 8;                // /256
  int blk = bx & 255;
  const float* src = (w == 0) ? wq : ((w == 1) ? wk : ((w == 2) ? wv : wo));
  u16* dst = wb + (size_t)w * NW;
  int i = (blk * 256 + (int)threadIdx.x) * 4;
  const float4 val = *(const float4*)(src + i);
  union { uint2 u; u16 h[4]; } pk;
  pk.h[0] = f2bf(val.x); pk.h[1] = f2bf(val.y);
  pk.h[2] = f2bf(val.z); pk.h[3] = f2bf(val.w);
  *(uint2*)(dst + i) = pk.u;
}

// ---------------- QKV projection GEMM (BK=64, two-half LDS, fused cvt) ------
// R10-verified: half the barriers vs BK=32, aux -9.4us. Identical per-half
// fragment addressing, staging bytes, MFMA count; fragment registers unchanged.
__global__ __launch_bounds__(256) void gemm_qkv(
    const float* __restrict__ Xq, const float* __restrict__ Xk, const float* __restrict__ Xv,
    const u16* __restrict__ Wb,
    const float* __restrict__ bq, const float* __restrict__ bk, const float* __restrict__ bv,
    u16* __restrict__ Qp, u16* __restrict__ Kp, u16* __restrict__ Vt) {
  const int z = blockIdx.z;
  const float* X = (z == 0) ? Xq : ((z == 1) ? Xk : Xv);
  const u16* W = Wb + (size_t)z * (HID * HID);
  const float* bias = (z == 0) ? bq : ((z == 1) ? bk : bv);

  __shared__ u16 As[2][128 * 32];
  __shared__ u16 Bs[2][128 * 32];

  const int tid = threadIdx.x;
  const int wid = tid >> 6, lane = tid & 63;
  const int wm = wid >> 1, wn = wid & 1;
  const int quad = lane >> 4, l16 = lane & 15;
  const int m0 = (int)blockIdx.x * 128, n0 = (int)blockIdx.y * 128;
  const int srow = lane >> 2;
  const int scol = (lane & 3) * 8;

  floatx4 acc[4][4];
#pragma unroll
  for (int i = 0; i < 4; i++)
#pragma unroll
    for (int j = 0; j < 4; j++) acc[i][j] = floatx4{0.f, 0.f, 0.f, 0.f};

  for (int k0 = 0; k0 < HID; k0 += 64) {
#pragma unroll
    for (int half = 0; half < 2; half++) {
#pragma unroll
      for (int r = 0; r < 2; r++) {
        int row = r * 64 + wid * 16 + srow;
        const float* srcp = X + (size_t)(m0 + row) * HID + k0 + half * 32 + scol;
        float4 p0 = *(const float4*)srcp;
        float4 p1 = *(const float4*)(srcp + 4);
        union { unsigned u[4]; short8 s; } pka;
        pka.u[0] = cvt_pk_bf16(p0.x, p0.y);
        pka.u[1] = cvt_pk_bf16(p0.z, p0.w);
        pka.u[2] = cvt_pk_bf16(p1.x, p1.y);
        pka.u[3] = cvt_pk_bf16(p1.z, p1.w);
        *(short8*)&As[half][(r * 64 + wid * 16) * 32 + lane * 8] = pka.s;
        gll16(W + (size_t)(n0 + row) * HID + k0 + half * 32 + scol,
              &Bs[half][(r * 64 + wid * 16) * 32]);
      }
    }
    __syncthreads();
#pragma unroll
    for (int kq = 0; kq < 2; kq++) {
      short8 af[4], bf[4];
#pragma unroll
      for (int mt = 0; mt < 4; mt++)
        af[mt] = *(const short8*)&As[kq][(wm * 64 + mt * 16 + l16) * 32 + quad * 8];
#pragma unroll
      for (int nt = 0; nt < 4; nt++)
        bf[nt] = *(const short8*)&Bs[kq][(wn * 64 + nt * 16 + l16) * 32 + quad * 8];
#pragma unroll
      for (int mt = 0; mt < 4; mt++)
#pragma unroll
        for (int nt = 0; nt < 4; nt++)
          acc[mt][nt] = __builtin_amdgcn_mfma_f32_16x16x32_bf16(af[mt], bf[nt], acc[mt][nt], 0, 0, 0);
    }
    __syncthreads();
  }

#pragma unroll
  for (int mt = 0; mt < 4; mt++) {
#pragma unroll
    for (int nt = 0; nt < 4; nt++) {
      int ncol = n0 + wn * 64 + nt * 16 + l16;
      float bias_v = bias[ncol];
      int h = ncol >> 6, d = ncol & 63;
#pragma unroll
      for (int r = 0; r < 4; r++) {
        int mrow = m0 + wm * 64 + mt * 16 + quad * 4 + r;
        float v = acc[mt][nt][r] + bias_v;
        int b = mrow >> 12, s = mrow & (SEQ - 1);
        size_t base = (size_t)(b * NH + h) * SEQ * HD;
        if (z == 2) {
          int kk = ((s >> 2) & 3) * 8 + ((s >> 4) & 1) * 4 + (s & 3);
          size_t idx = base + (size_t)(s >> 5) * 2048 + (d >> 4) * 512
                     + (kk >> 3) * 128 + (d & 15) * 8 + (kk & 7);
          Vt[idx] = f2bf(v);
        } else {
          size_t idx = base + (size_t)(s >> 4) * 1024 + (d >> 3) * 128 + (s & 15) * 8 + (d & 7);
          if (z == 0) Qp[idx] = f2bf(v * 0.18033688f);   // 0.125*log2(e)
          else        Kp[idx] = f2bf(v);
        }
      }
    }
  }
}

// ---------------- output projection GEMM (fused split-K combine) ------------
__global__ __launch_bounds__(256) void gemm_out(
    const u16* __restrict__ Opb, const float* __restrict__ Lp,
    const u16* __restrict__ W,
    const float* __restrict__ bias, float* __restrict__ out) {
  __shared__ u16 As[128 * 32];
  __shared__ u16 Bs[64 * 32];

  const int tid = threadIdx.x;
  const int wid = tid >> 6, lane = tid & 63;
  const int wm = wid >> 1, wn = wid & 1;
  const int quad = lane >> 4, l16 = lane & 15;
  const int m0 = (int)blockIdx.x * 128, n0 = (int)blockIdx.y * 64;
  const int srow = lane >> 2;
  const int scol = (lane & 3) * 8;

  float invl[2][NH];
#pragma unroll
  for (int r = 0; r < 2; r++) {
    int mrow = m0 + r * 64 + wid * 16 + srow;
    int b = mrow >> 12, qq = mrow & (SEQ - 1);
#pragma unroll
    for (int h = 0; h < NH; h++) {
      float s = 0.f;
#pragma unroll
      for (int sp = 0; sp < SPLITK; sp++)
        s += Lp[(size_t)(sp * NBH + b * NH + h) * SEQ + qq];
      invl[r][h] = 1.f / s;
    }
  }

  floatx4 acc[4][2];
#pragma unroll
  for (int i = 0; i < 4; i++)
#pragma unroll
    for (int j = 0; j < 2; j++) acc[i][j] = floatx4{0.f, 0.f, 0.f, 0.f};

#pragma unroll
  for (int kb = 0; kb < 16; kb++) {
    const int k0 = kb * 32;
    const int h = k0 >> 6;                 // compile-time per unrolled iter
    const int d = (k0 + scol) & 63;
#pragma unroll
    for (int r = 0; r < 2; r++) {
      int mrow = m0 + r * 64 + wid * 16 + srow;
      int b = mrow >> 12, qq = mrow & (SEQ - 1);
      int bh = b * NH + h;
      float a0 = 0.f, a1 = 0.f, a2 = 0.f, a3 = 0.f, a4 = 0.f, a5 = 0.f, a6 = 0.f, a7 = 0.f;
#pragma unroll
      for (int sp = 0; sp < SPLITK; sp++) {
        const u16* p = Opb + ((size_t)(sp * NBH + bh) * SEQ + qq) * HD + d;
        short8 vv = *(const short8*)p;
        a0 += bf2f((u16)vv[0]); a1 += bf2f((u16)vv[1]);
        a2 += bf2f((u16)vv[2]); a3 += bf2f((u16)vv[3]);
        a4 += bf2f((u16)vv[4]); a5 += bf2f((u16)vv[5]);
        a6 += bf2f((u16)vv[6]); a7 += bf2f((u16)vv[7]);
      }
      float inv = invl[r][h];
      union { unsigned u[4]; short8 s; } pka;
      pka.u[0] = cvt_pk_bf16(a0 * inv, a1 * inv);
      pka.u[1] = cvt_pk_bf16(a2 * inv, a3 * inv);
      pka.u[2] = cvt_pk_bf16(a4 * inv, a5 * inv);
      pka.u[3] = cvt_pk_bf16(a6 * inv, a7 * inv);
      *(short8*)&As[(r * 64 + wid * 16) * 32 + lane * 8] = pka.s;
    }
    {
      int row = wid * 16 + srow;
      gll16(W + (size_t)(n0 + row) * HID + k0 + scol, &Bs[(wid * 16) * 32]);
    }
    __syncthreads();
    short8 af[4], bfr[2];
#pragma unroll
    for (int mt = 0; mt < 4; mt++)
      af[mt] = *(const short8*)&As[(wm * 64 + mt * 16 + l16) * 32 + quad * 8];
#pragma unroll
    for (int nt = 0; nt < 2; nt++)
      bfr[nt] = *(const short8*)&Bs[(wn * 32 + nt * 16 + l16) * 32 + quad * 8];
#pragma unroll
    for (int mt = 0; mt < 4; mt++)
#pragma unroll
      for (int nt = 0; nt < 2; nt++)
        acc[mt][nt] = __builtin_amdgcn_mfma_f32_16x16x32_bf16(af[mt], bfr[nt], acc[mt][nt], 0, 0, 0);
    __syncthreads();
  }

#pragma unroll
  for (int mt = 0; mt < 4; mt++) {
#pragma unroll
    for (int nt = 0; nt < 2; nt++) {
      int ncol = n0 + wn * 32 + nt * 16 + l16;
      float bias_v = bias[ncol];
#pragma unroll
      for (int r = 0; r < 4; r++) {
        int mrow = m0 + wm * 64 + mt * 16 + quad * 4 + r;
        out[(size_t)mrow * HID + ncol] = acc[mt][nt][r] + bias_v;
      }
    }
  }
}

// ---------------- flash attention v15 (R9-verified, 82.6us): no setprio -----
// 64 VGPR, 4 waves, KVBLK=64, SPLITK=2, grid 1024 = 4 blocks/CU.
__global__ __launch_bounds__(256) void attn_kernel(
    const u16* __restrict__ Qp, const u16* __restrict__ Kp,
    const u16* __restrict__ Vt, u16* __restrict__ Opb, float* __restrict__ Lp) {
  const int bh = blockIdx.y;
  const int sp = blockIdx.z;
  const int q0 = (int)blockIdx.x * 128;
  const u16* Qh = Qp + (size_t)bh * SEQ * HD;
  const u16* Kh = Kp + (size_t)bh * SEQ * HD;
  const u16* Vh = Vt + (size_t)bh * SEQ * HD;

  __shared__ u16 Ks[2][4096];   // 8 KB per buffer: 64 kv x 64 d
  __shared__ u16 Vs[2][4096];

  const int tid = threadIdx.x;
  const int wid = tid >> 6, lane = tid & 63;
  const int quad = lane >> 4, l16 = lane & 15;

  short8 qf[2][2];
#pragma unroll
  for (int kq = 0; kq < 2; kq++)
#pragma unroll
    for (int n = 0; n < 2; n++)
      qf[kq][n] = *(const short8*)(Qh + (size_t)(q0 / 16 + wid * 2 + n) * 1024 + (kq * 4 + quad) * 128 + l16 * 8);

  float l_part[2] = {0.f, 0.f};
  floatx4 o[2][4];
#pragma unroll
  for (int m = 0; m < 2; m++)
#pragma unroll
    for (int dt = 0; dt < 4; dt++) o[m][dt] = floatx4{0.f, 0.f, 0.f, 0.f};

  const int kv_lo = sp * (SEQ / SPLITK), kv_hi = kv_lo + SEQ / SPLITK;

  auto stage = [&](int buf, int kv0) {
    const u16* kg = Kh + (size_t)(kv0 >> 4) * 1024;   // == kv0*64, both layouts
    const u16* vg = Vh + (size_t)(kv0 >> 4) * 1024;
#pragma unroll
    for (int r = 0; r < 2; r++) {
      int c = wid + r * 4;
      gll16(kg + c * 512 + lane * 8, &Ks[buf][c * 512]);
      gll16(vg + c * 512 + lane * 8, &Vs[buf][c * 512]);
    }
  };

  stage(0, kv_lo);
  __syncthreads();

  int ibuf = 0;
  for (int kv0 = kv_lo; kv0 < kv_hi; kv0 += 64) {
    if (kv0 + 64 < kv_hi) stage(ibuf ^ 1, kv0 + 64);

#pragma unroll
    for (int gg = 0; gg < 2; gg++) {             // 32-kv group = score tiles A,B
      const u16* Kb = &Ks[ibuf][gg * 2048];
      short8 akA0 = *(const short8*)&Kb[quad * 128 + l16 * 8];
      short8 akA1 = *(const short8*)&Kb[(4 + quad) * 128 + l16 * 8];
      short8 akB0 = *(const short8*)&Kb[1024 + quad * 128 + l16 * 8];
      short8 akB1 = *(const short8*)&Kb[1024 + (4 + quad) * 128 + l16 * 8];
      short8 vf[4];
#pragma unroll
      for (int dt = 0; dt < 4; dt++)
        vf[dt] = *(const short8*)&Vs[ibuf][gg * 2048 + dt * 512 + quad * 128 + l16 * 8];

      floatx4 stA[2], stB[2];
#pragma unroll
      for (int n = 0; n < 2; n++) {
        stA[n] = __builtin_amdgcn_mfma_f32_16x16x32_bf16(akA0, qf[0][n], floatx4{0.f,0.f,0.f,0.f}, 0, 0, 0);
        stB[n] = __builtin_amdgcn_mfma_f32_16x16x32_bf16(akB0, qf[0][n], floatx4{0.f,0.f,0.f,0.f}, 0, 0, 0);
        stA[n] = __builtin_amdgcn_mfma_f32_16x16x32_bf16(akA1, qf[1][n], stA[n], 0, 0, 0);
        stB[n] = __builtin_amdgcn_mfma_f32_16x16x32_bf16(akB1, qf[1][n], stB[n], 0, 0, 0);
      }

#pragma unroll
      for (int n = 0; n < 2; n++) {
        float a0 = __builtin_amdgcn_exp2f(stA[n][0]);
        float a1 = __builtin_amdgcn_exp2f(stA[n][1]);
        float a2 = __builtin_amdgcn_exp2f(stA[n][2]);
        float a3 = __builtin_amdgcn_exp2f(stA[n][3]);
        float b0 = __builtin_amdgcn_exp2f(stB[n][0]);
        float b1 = __builtin_amdgcn_exp2f(stB[n][1]);
        float b2 = __builtin_amdgcn_exp2f(stB[n][2]);
        float b3 = __builtin_amdgcn_exp2f(stB[n][3]);
        l_part[n] += ((a0 + a1) + (a2 + a3)) + ((b0 + b1) + (b2 + b3));
        union { unsigned u[4]; short8 s; } pk;
        pk.u[0] = cvt_pk_bf16(a0, a1);
        pk.u[1] = cvt_pk_bf16(a2, a3);
        pk.u[2] = cvt_pk_bf16(b0, b1);
        pk.u[3] = cvt_pk_bf16(b2, b3);
#pragma unroll
        for (int dt = 0; dt < 4; dt++)
          o[n][dt] = __builtin_amdgcn_mfma_f32_16x16x32_bf16(pk.s, vf[dt], o[n][dt], 0, 0, 0);
      }
    }
    __syncthreads();
    ibuf ^= 1;
  }

#pragma unroll
  for (int n = 0; n < 2; n++) {
    l_part[n] += __shfl_xor(l_part[n], 16);
    l_part[n] += __shfl_xor(l_part[n], 32);
  }
  u16* Oph = Opb + (size_t)(sp * NBH + bh) * SEQ * HD;
  float* Lph = Lp + (size_t)(sp * NBH + bh) * SEQ;
  if (quad == 0) {
#pragma unroll
    for (int n = 0; n < 2; n++)
      Lph[q0 + wid * 32 + n * 16 + l16] = l_part[n];
  }
#pragma unroll
  for (int m = 0; m < 2; m++) {
#pragma unroll
    for (int r = 0; r < 4; r++) {
      int s = q0 + wid * 32 + m * 16 + quad * 4 + r;
#pragma unroll
      for (int dt = 0; dt < 4; dt++)
        Oph[(size_t)s * HD + dt * 16 + l16] = f2bf(o[m][dt][r]);
    }
  }
}

extern "C" void kernel_launch(void* const* d_in, const int* in_sizes, int n_in,
                              void* d_out, int out_size, void* d_ws, size_t ws_size,
                              hipStream_t stream) {
  const float* q  = (const float*)d_in[0];
  const float* k  = (const float*)d_in[1];
  const float* v  = (const float*)d_in[2];
  const float* Wq = (const float*)d_in[3];
  const float* bq = (const float*)d_in[4];
  const float* Wk = (const float*)d_in[5];
  const float* bk = (const float*)d_in[6];
  const float* Wv = (const float*)d_in[7];
  const float* bv = (const float*)d_in[8];
  const float* Wo = (const float*)d_in[9];
  const float* bo = (const float*)d_in[10];

  u16* wsb = (u16*)d_ws;
  const size_t NW = (size_t)HID * HID;     // 262144
  const size_t NX = (size_t)M_TOT * HID;   // 4194304
  u16* Wb = wsb;            // Wq,Wk,Wv,Wo bf16 (4*NW)
  u16* Qp = wsb + 4 * NW;
  u16* Kp = Qp + NX;
  u16* Vt = Kp + NX;
  u16* Opb = Vt + NX;                          // 2*16*4096*64 bf16 = 16.8 MB
  float* Lp = (float*)(Opb + (size_t)SPLITK * NBH * SEQ * HD);  // 2*16*4096 fp32 = 512 KB

  dim3 blk(256);
  cvt_w<<<dim3(1024), blk, 0, stream>>>(Wq, Wk, Wv, Wo, Wb);
  gemm_qkv<<<dim3(64, 4, 3), blk, 0, stream>>>(q, k, v, Wb, bq, bk, bv, Qp, Kp, Vt);
  attn_kernel<<<dim3(32, NBH, SPLITK), blk, 0, stream>>>(Qp, Kp, Vt, Opb, Lp);
  gemm_out<<<dim3(64, 8), blk, 0, stream>>>(Opb, Lp, Wb + 3 * NW, bo, (float*)d_out);
}